// Round 3
// baseline (9677.203 us; speedup 1.0000x reference)
//
#include <hip/hip_runtime.h>
#include <hip/hip_bf16.h>

#define TDIM 4096
#define BDIM 64
#define FDIM 128
#define HDIM 512
#define ODIM 128
#define KWIN 32

typedef __attribute__((ext_vector_type(8))) short short8;
typedef __attribute__((ext_vector_type(4))) float floatx4;
typedef __attribute__((ext_vector_type(4))) float float4v;

__device__ __forceinline__ unsigned short f2bf(float f) {
  unsigned int u = __float_as_uint(f);
  u += 0x7fffu + ((u >> 16) & 1u);
  return (unsigned short)(u >> 16);
}
__device__ __forceinline__ float bf2f(unsigned short s) {
  return __uint_as_float(((unsigned int)s) << 16);
}
__device__ __forceinline__ unsigned int cvt_pk_bf16(float lo, float hi) {
  unsigned int r;
  asm("v_cvt_pk_bf16_f32 %0, %1, %2" : "=v"(r) : "v"(lo), "v"(hi));
  return r;
}

// ---------------------------------------------------------------------------
// Prep: frac-diff + input projection, SWAPPED orientation.
// Block = (16 time steps, 16-batch group g). 512 threads (8 waves).
// xp dword layout (packed bf16 pairs, pre = x_f@Wih^T + bih + bhh):
//   for scan lane l (lr=l&15=batch, lq=l>>4), wave w, m-tile mt, pair pr:
//   value = pre[batch = g*16+lr][hcol = w*64+mt*16+lq*4+2*pr+{0,1}]
//   idx   = t*16384 + g*4096 + ((w*4+mt)*2+pr)*64 + l
// ---------------------------------------------------------------------------
__global__ __launch_bounds__(512, 1)
void prep_kernel(const float* __restrict__ x, const float* __restrict__ bd,
                 const float* __restrict__ Wih, const float* __restrict__ bih,
                 const float* __restrict__ bhh, unsigned int* __restrict__ xp)
{
  __shared__ float wpi[33 * 128];                 // 16.9 KB
  __shared__ __align__(16) float xslab[2][48 * 128];  // 48 KB double-buffered x
  __shared__ __align__(16) short xf[256 * 136];   // 69.6 KB rows: tloc*16+bloc

  const int tid = threadIdx.x;
  const int tc = blockIdx.x;          // 0..255 (16-t chunks)
  const int g  = blockIdx.y;          // 0..3  (batch group)
  const int t0 = tc * 16;

  // ARFIMA coefficients pi_0..pi_32 per feature
  if (tid < 128) {
    float d = 0.5f / (1.0f + __expf(-bd[tid]));
    float pi = 1.0f;
    wpi[tid] = pi;
    for (int i = 0; i < 32; ++i) {
      pi *= ((float)i - d) / (float)(i + 1);
      wpi[(i + 1) * 128 + tid] = pi;
    }
  }

  // stage slab for bloc=0: rows t0-32..t0+15, batch g*16
  {
    int bb = g * 16;
    #pragma unroll
    for (int rep = 0; rep < 3; ++rep) {
      int flat = rep * 512 + tid;
      int row = flat >> 5, c4 = flat & 31;
      int t = t0 + row - 32;
      float4v v = {0.f, 0.f, 0.f, 0.f};
      if (t >= 0) v = *(const float4v*)(x + ((size_t)t * BDIM + bb) * FDIM + (size_t)c4 * 4);
      *(float4v*)&xslab[0][row * 128 + c4 * 4] = v;
    }
  }
  __syncthreads();

  // per-thread pi weights for feature f
  const int f = tid & 127, tl = tid >> 7;
  float wv[33];
  #pragma unroll
  for (int j = 0; j < 33; ++j) wv[j] = wpi[j * 128 + f];

  // frac-diff 16 batches sequentially, double-buffered slab
  for (int bloc = 0; bloc < 16; ++bloc) {
    int cur = bloc & 1;
    float4v tmp[3];
    if (bloc < 15) {
      int bb = g * 16 + bloc + 1;
      #pragma unroll
      for (int rep = 0; rep < 3; ++rep) {
        int flat = rep * 512 + tid;
        int row = flat >> 5, c4 = flat & 31;
        int t = t0 + row - 32;
        float4v v = {0.f, 0.f, 0.f, 0.f};
        if (t >= 0) v = *(const float4v*)(x + ((size_t)t * BDIM + bb) * FDIM + (size_t)c4 * 4);
        tmp[rep] = v;
      }
    }
    #pragma unroll
    for (int s = 0; s < 4; ++s) {
      int tloc = tl * 4 + s;
      float acc = 0.f;
      #pragma unroll
      for (int j = 0; j < 33; ++j) acc += wv[j] * xslab[cur][(tloc + 32 - j) * 128 + f];
      xf[(tloc * 16 + bloc) * 136 + f] = (short)f2bf(acc);
    }
    if (bloc < 15) {
      #pragma unroll
      for (int rep = 0; rep < 3; ++rep) {
        int flat = rep * 512 + tid;
        int row = flat >> 5, c4 = flat & 31;
        *(float4v*)&xslab[cur ^ 1][row * 128 + c4 * 4] = tmp[rep];
      }
    }
    __syncthreads();
  }

  // --- swapped GEMM: D[hcol][row] = Wih[hcol][:] . xf[row][:] ---
  const int w = tid >> 6, l = tid & 63;
  const int lr = l & 15, lq = l >> 4;

  short8 wf[4][4];      // [mt][kc]
  float4v bias4[4];
  #pragma unroll
  for (int mt = 0; mt < 4; ++mt) {
    #pragma unroll
    for (int kc = 0; kc < 4; ++kc) {
      int hcol = w * 64 + mt * 16 + lr;
      const float* src = Wih + (size_t)hcol * FDIM + kc * 32 + lq * 8;
      float4v f0 = *(const float4v*)src;
      float4v f1 = *(const float4v*)(src + 4);
      short8 s;
      s[0] = (short)f2bf(f0[0]); s[1] = (short)f2bf(f0[1]);
      s[2] = (short)f2bf(f0[2]); s[3] = (short)f2bf(f0[3]);
      s[4] = (short)f2bf(f1[0]); s[5] = (short)f2bf(f1[1]);
      s[6] = (short)f2bf(f1[2]); s[7] = (short)f2bf(f1[3]);
      wf[mt][kc] = s;
    }
    int hb = w * 64 + mt * 16 + lq * 4;
    float4v b0 = *(const float4v*)(bih + hb);
    float4v b1 = *(const float4v*)(bhh + hb);
    bias4[mt] = b0 + b1;
  }

  #pragma unroll
  for (int ntile = 0; ntile < 16; ++ntile) {   // ntile = tloc
    floatx4 acc[4];
    #pragma unroll
    for (int kc = 0; kc < 4; ++kc) {
      short8 b = *(const short8*)&xf[(ntile * 16 + lr) * 136 + kc * 32 + lq * 8];
      #pragma unroll
      for (int mt = 0; mt < 4; ++mt) {
        floatx4 c = (kc == 0) ? (floatx4){0.f, 0.f, 0.f, 0.f} : acc[mt];
        acc[mt] = __builtin_amdgcn_mfma_f32_16x16x32_bf16(wf[mt][kc], b, c, 0, 0, 0);
      }
    }
    int t = t0 + ntile;
    #pragma unroll
    for (int mt = 0; mt < 4; ++mt) {
      floatx4 s = acc[mt] + bias4[mt];
      unsigned int d0 = cvt_pk_bf16(s[0], s[1]);
      unsigned int d1 = cvt_pk_bf16(s[2], s[3]);
      size_t base = (size_t)t * 16384 + (size_t)(g * 4096) + (size_t)((w * 4 + mt) * 2) * 64 + l;
      xp[base] = d0;
      xp[base + 64] = d1;
    }
  }
}

// ---------------------------------------------------------------------------
// Scan: 4 WGs (batch groups of 16) x 512 threads (8 waves, 2/SIMD).
// Swapped MFMA: D[hcol][batch] = W_hh[hcol][k] . h[batch][k].
// Wave w owns hcols [w*64, w*64+64). A-frags (W_hh): kc 0..11 in regs,
// kc 12..15 in LDS. h in LDS [16 batch][520] bf16. 2 barriers/step.
// ---------------------------------------------------------------------------
__global__ __launch_bounds__(512, 2)
void scan_kernel(const float* __restrict__ Whh, const unsigned int* __restrict__ xp,
                 const float* __restrict__ Who, const float* __restrict__ bho,
                 float* __restrict__ out)
{
  __shared__ __align__(16) short h_lds[16 * 520];        // 16.6 KB [batch][hcol]
  __shared__ __align__(16) short8 w_lds[4 * 8 * 4 * 64]; // 128 KB [(kc-12)][w][mt][lane]

  const int tid = threadIdx.x;
  const int g = blockIdx.x;
  const int w = tid >> 6, l = tid & 63;
  const int lr = l & 15, lq = l >> 4;

  // A-frags: A[m=hcol][k]: lane holds Whh[w*64+mt*16+lr][kc*32+lq*8 .. +8]
  short8 wreg[48];   // kc 0..11 x mt 0..3  -> wreg[kc*4+mt]
  #pragma unroll
  for (int kc = 0; kc < 16; ++kc)
    #pragma unroll
    for (int mt = 0; mt < 4; ++mt) {
      int hcol = w * 64 + mt * 16 + lr;
      const float* src = Whh + (size_t)hcol * HDIM + kc * 32 + lq * 8;
      float4v f0 = *(const float4v*)src;
      float4v f1 = *(const float4v*)(src + 4);
      short8 s;
      s[0] = (short)f2bf(f0[0]); s[1] = (short)f2bf(f0[1]);
      s[2] = (short)f2bf(f0[2]); s[3] = (short)f2bf(f0[3]);
      s[4] = (short)f2bf(f1[0]); s[5] = (short)f2bf(f1[1]);
      s[6] = (short)f2bf(f1[2]); s[7] = (short)f2bf(f1[3]);
      if (kc < 12) wreg[kc * 4 + mt] = s;
      else w_lds[(((kc - 12) * 8 + w) * 4 + mt) * 64 + l] = s;
    }

  for (int i = tid; i < 16 * 520; i += 512) h_lds[i] = 0;
  __syncthreads();

  const unsigned int* xpb = xp + (size_t)(g * 4096 + w * 512 + l);
  const float C2 = 2.8853900818f;   // 2/ln2

  #pragma unroll 1
  for (int t = 0; t < TDIM; ++t) {
    // xp loads (consumed after barrier 1; latency hidden under MFMA)
    unsigned int u[8];
    const unsigned int* p = xpb + (size_t)t * 16384;
    #pragma unroll
    for (int j = 0; j < 8; ++j) u[j] = p[j * 64];

    // B-frag: h[batch=lr][kc*32+lq*8 ..]; 8 independent acc chains
    floatx4 accA[4], accB[4];
    #pragma unroll
    for (int kc = 0; kc < 16; ++kc) {
      short8 b = *(const short8*)&h_lds[lr * 520 + kc * 32 + lq * 8];
      #pragma unroll
      for (int mt = 0; mt < 4; ++mt) {
        short8 a = (kc < 12) ? wreg[kc * 4 + mt]
                             : w_lds[(((kc - 12) * 8 + w) * 4 + mt) * 64 + l];
        if (kc == 0)
          accA[mt] = __builtin_amdgcn_mfma_f32_16x16x32_bf16(a, b, (floatx4){0.f,0.f,0.f,0.f}, 0, 0, 0);
        else if (kc < 8)
          accA[mt] = __builtin_amdgcn_mfma_f32_16x16x32_bf16(a, b, accA[mt], 0, 0, 0);
        else if (kc == 8)
          accB[mt] = __builtin_amdgcn_mfma_f32_16x16x32_bf16(a, b, (floatx4){0.f,0.f,0.f,0.f}, 0, 0, 0);
        else
          accB[mt] = __builtin_amdgcn_mfma_f32_16x16x32_bf16(a, b, accB[mt], 0, 0, 0);
      }
    }
    __syncthreads();   // all reads of h done

    // tanh + packed write: lane's 4 values = 4 consecutive hcols, batch lr
    #pragma unroll
    for (int mt = 0; mt < 4; ++mt) {
      floatx4 s = accA[mt] + accB[mt];
      unsigned int u0 = u[mt * 2], u1 = u[mt * 2 + 1];
      float pre0 = s[0] + __uint_as_float(u0 << 16);
      float pre1 = s[1] + __uint_as_float(u0 & 0xffff0000u);
      float pre2 = s[2] + __uint_as_float(u1 << 16);
      float pre3 = s[3] + __uint_as_float(u1 & 0xffff0000u);
      float t0v = 1.0f - 2.0f * __builtin_amdgcn_rcpf(exp2f(pre0 * C2) + 1.0f);
      float t1v = 1.0f - 2.0f * __builtin_amdgcn_rcpf(exp2f(pre1 * C2) + 1.0f);
      float t2v = 1.0f - 2.0f * __builtin_amdgcn_rcpf(exp2f(pre2 * C2) + 1.0f);
      float t3v = 1.0f - 2.0f * __builtin_amdgcn_rcpf(exp2f(pre3 * C2) + 1.0f);
      unsigned int d0 = cvt_pk_bf16(t0v, t1v);
      unsigned int d1 = cvt_pk_bf16(t2v, t3v);
      uint2 dv; dv.x = d0; dv.y = d1;
      *(uint2*)&h_lds[lr * 520 + w * 64 + mt * 16 + lq * 4] = dv;
    }
    __syncthreads();   // writes visible
  }

  // hT (output 1)
  for (int i = tid; i < 16 * 512; i += 512) {
    int row = i >> 9, col = i & 511;
    out[(size_t)ODIM * BDIM + ((size_t)(g * 16 + row)) * HDIM + col] =
        bf2f((unsigned short)h_lds[row * 520 + col]);
  }

  // output projection: D[batch][o] = h[batch][:] . Who[o][:]
  floatx4 oacc;
  #pragma unroll
  for (int kc = 0; kc < 16; ++kc) {
    short8 a = *(const short8*)&h_lds[lr * 520 + kc * 32 + lq * 8];
    int o = w * 16 + lr;
    const float* src = Who + (size_t)o * HDIM + kc * 32 + lq * 8;
    float4v f0 = *(const float4v*)src;
    float4v f1 = *(const float4v*)(src + 4);
    short8 s;
    s[0] = (short)f2bf(f0[0]); s[1] = (short)f2bf(f0[1]);
    s[2] = (short)f2bf(f0[2]); s[3] = (short)f2bf(f0[3]);
    s[4] = (short)f2bf(f1[0]); s[5] = (short)f2bf(f1[1]);
    s[6] = (short)f2bf(f1[2]); s[7] = (short)f2bf(f1[3]);
    floatx4 c = (kc == 0) ? (floatx4){0.f, 0.f, 0.f, 0.f} : oacc;
    oacc = __builtin_amdgcn_mfma_f32_16x16x32_bf16(a, s, c, 0, 0, 0);
  }
  #pragma unroll
  for (int rr = 0; rr < 4; ++rr) {
    int o = w * 16 + lr;
    int row = lq * 4 + rr;
    out[((size_t)(g * 16 + row)) * ODIM + o] = oacc[rr] + bho[o];
  }
}

// ---------------------------------------------------------------------------
extern "C" void kernel_launch(void* const* d_in, const int* in_sizes, int n_in,
                              void* d_out, int out_size, void* d_ws, size_t ws_size,
                              hipStream_t stream) {
  const float* x   = (const float*)d_in[0];
  const float* bd  = (const float*)d_in[1];
  const float* Wih = (const float*)d_in[2];
  const float* bih = (const float*)d_in[3];
  const float* Whh = (const float*)d_in[4];
  const float* bhh = (const float*)d_in[5];
  const float* Who = (const float*)d_in[6];
  const float* bho = (const float*)d_in[7];
  float* out = (float*)d_out;
  unsigned int* xp = (unsigned int*)d_ws;   // T*B*H*2 = 268.4 MB

  prep_kernel<<<dim3(TDIM / 16, 4), 512, 0, stream>>>(x, bd, Wih, bih, bhh, xp);
  scan_kernel<<<dim3(4), 512, 0, stream>>>(Whh, xp, Who, bho, out);
}

// Round 4
// 5918.824 us; speedup vs baseline: 1.6350x; 1.6350x over previous
//
#include <hip/hip_runtime.h>
#include <hip/hip_bf16.h>

#define TDIM 4096
#define BDIM 64
#define FDIM 128
#define HDIM 512
#define ODIM 128
#define KWIN 32

typedef __attribute__((ext_vector_type(8))) short short8;
typedef __attribute__((ext_vector_type(4))) float floatx4;
typedef __attribute__((ext_vector_type(4))) float float4v;
typedef __attribute__((ext_vector_type(4))) int int4v;
typedef __attribute__((ext_vector_type(8))) unsigned int uintx8;

__device__ __forceinline__ unsigned short f2bf(float f) {
  unsigned int u = __float_as_uint(f);
  u += 0x7fffu + ((u >> 16) & 1u);
  return (unsigned short)(u >> 16);
}
__device__ __forceinline__ float bf2f(unsigned short s) {
  return __uint_as_float(((unsigned int)s) << 16);
}
__device__ __forceinline__ unsigned int cvt_pk_bf16(float lo, float hi) {
  unsigned int r;
  asm("v_cvt_pk_bf16_f32 %0, %1, %2" : "=v"(r) : "v"(lo), "v"(hi));
  return r;
}

// ---------------------------------------------------------------------------
// Prep: frac-diff + input projection, swapped orientation (unchanged from R3).
// xp dword layout (packed bf16 pairs, pre = x_f@Wih^T + bih + bhh):
//   scan lane l (lr=batch, lq), wave w, m-tile mt, pair pr:
//   value = pre[batch=g*16+lr][hcol = w*64+mt*16+lq*4+2*pr+{0,1}]
//   idx   = t*16384 + g*4096 + ((w*4+mt)*2+pr)*64 + l
// ---------------------------------------------------------------------------
__global__ __launch_bounds__(512, 1)
void prep_kernel(const float* __restrict__ x, const float* __restrict__ bd,
                 const float* __restrict__ Wih, const float* __restrict__ bih,
                 const float* __restrict__ bhh, unsigned int* __restrict__ xp)
{
  __shared__ float wpi[33 * 128];
  __shared__ __align__(16) float xslab[2][48 * 128];
  __shared__ __align__(16) short xf[256 * 136];

  const int tid = threadIdx.x;
  const int tc = blockIdx.x;
  const int g  = blockIdx.y;
  const int t0 = tc * 16;

  if (tid < 128) {
    float d = 0.5f / (1.0f + __expf(-bd[tid]));
    float pi = 1.0f;
    wpi[tid] = pi;
    for (int i = 0; i < 32; ++i) {
      pi *= ((float)i - d) / (float)(i + 1);
      wpi[(i + 1) * 128 + tid] = pi;
    }
  }

  {
    int bb = g * 16;
    #pragma unroll
    for (int rep = 0; rep < 3; ++rep) {
      int flat = rep * 512 + tid;
      int row = flat >> 5, c4 = flat & 31;
      int t = t0 + row - 32;
      float4v v = {0.f, 0.f, 0.f, 0.f};
      if (t >= 0) v = *(const float4v*)(x + ((size_t)t * BDIM + bb) * FDIM + (size_t)c4 * 4);
      *(float4v*)&xslab[0][row * 128 + c4 * 4] = v;
    }
  }
  __syncthreads();

  const int f = tid & 127, tl = tid >> 7;
  float wv[33];
  #pragma unroll
  for (int j = 0; j < 33; ++j) wv[j] = wpi[j * 128 + f];

  for (int bloc = 0; bloc < 16; ++bloc) {
    int cur = bloc & 1;
    float4v tmp[3];
    if (bloc < 15) {
      int bb = g * 16 + bloc + 1;
      #pragma unroll
      for (int rep = 0; rep < 3; ++rep) {
        int flat = rep * 512 + tid;
        int row = flat >> 5, c4 = flat & 31;
        int t = t0 + row - 32;
        float4v v = {0.f, 0.f, 0.f, 0.f};
        if (t >= 0) v = *(const float4v*)(x + ((size_t)t * BDIM + bb) * FDIM + (size_t)c4 * 4);
        tmp[rep] = v;
      }
    }
    #pragma unroll
    for (int s = 0; s < 4; ++s) {
      int tloc = tl * 4 + s;
      float acc = 0.f;
      #pragma unroll
      for (int j = 0; j < 33; ++j) acc += wv[j] * xslab[cur][(tloc + 32 - j) * 128 + f];
      xf[(tloc * 16 + bloc) * 136 + f] = (short)f2bf(acc);
    }
    if (bloc < 15) {
      #pragma unroll
      for (int rep = 0; rep < 3; ++rep) {
        int flat = rep * 512 + tid;
        int row = flat >> 5, c4 = flat & 31;
        *(float4v*)&xslab[cur ^ 1][row * 128 + c4 * 4] = tmp[rep];
      }
    }
    __syncthreads();
  }

  const int w = tid >> 6, l = tid & 63;
  const int lr = l & 15, lq = l >> 4;

  short8 wf[4][4];
  float4v bias4[4];
  #pragma unroll
  for (int mt = 0; mt < 4; ++mt) {
    #pragma unroll
    for (int kc = 0; kc < 4; ++kc) {
      int hcol = w * 64 + mt * 16 + lr;
      const float* src = Wih + (size_t)hcol * FDIM + kc * 32 + lq * 8;
      float4v f0 = *(const float4v*)src;
      float4v f1 = *(const float4v*)(src + 4);
      short8 s;
      s[0] = (short)f2bf(f0[0]); s[1] = (short)f2bf(f0[1]);
      s[2] = (short)f2bf(f0[2]); s[3] = (short)f2bf(f0[3]);
      s[4] = (short)f2bf(f1[0]); s[5] = (short)f2bf(f1[1]);
      s[6] = (short)f2bf(f1[2]); s[7] = (short)f2bf(f1[3]);
      wf[mt][kc] = s;
    }
    int hb = w * 64 + mt * 16 + lq * 4;
    float4v b0 = *(const float4v*)(bih + hb);
    float4v b1 = *(const float4v*)(bhh + hb);
    bias4[mt] = b0 + b1;
  }

  #pragma unroll
  for (int ntile = 0; ntile < 16; ++ntile) {
    floatx4 acc[4];
    #pragma unroll
    for (int kc = 0; kc < 4; ++kc) {
      short8 b = *(const short8*)&xf[(ntile * 16 + lr) * 136 + kc * 32 + lq * 8];
      #pragma unroll
      for (int mt = 0; mt < 4; ++mt) {
        floatx4 c = (kc == 0) ? (floatx4){0.f, 0.f, 0.f, 0.f} : acc[mt];
        acc[mt] = __builtin_amdgcn_mfma_f32_16x16x32_bf16(wf[mt][kc], b, c, 0, 0, 0);
      }
    }
    int t = t0 + ntile;
    #pragma unroll
    for (int mt = 0; mt < 4; ++mt) {
      floatx4 s = acc[mt] + bias4[mt];
      unsigned int d0 = cvt_pk_bf16(s[0], s[1]);
      unsigned int d1 = cvt_pk_bf16(s[2], s[3]);
      size_t base = (size_t)t * 16384 + (size_t)(g * 4096) + (size_t)((w * 4 + mt) * 2) * 64 + l;
      xp[base] = d0;
      xp[base + 64] = d1;
    }
  }
}

// ---------------------------------------------------------------------------
// Scan: 4 WGs x 512 threads (8 waves, 2/SIMD). W_hh quantized to i8 with
// per-row scale, fully register-resident (128 VGPR/wave). h in i8 LDS,
// double-buffered -> ONE barrier per step. mfma_i32_16x16x64_i8.
// D[hcol][batch]: C layout col=lane&15=batch, row=lq*4+reg=hcol (shape-fixed).
// ---------------------------------------------------------------------------
__global__ __launch_bounds__(512, 2)
void scan_kernel(const float* __restrict__ Whh, const unsigned int* __restrict__ xp,
                 const float* __restrict__ Who, const float* __restrict__ bho,
                 float* __restrict__ out)
{
  __shared__ __align__(16) unsigned char h8[2][16 * 544];  // 17.4 KB, stride 544
  __shared__ float smax[8][4][16];                          // 2 KB row-scale bounce
  __shared__ __align__(16) short hbf[16 * 520];             // epilogue bf16 h

  const int tid = threadIdx.x;
  const int g = blockIdx.x;
  const int w = tid >> 6, l = tid & 63;
  const int lr = l & 15, lq = l >> 4;

  // ---- per-row |max| of W_hh (rows = this wave's hcols) ----
  float rmax[4];
  #pragma unroll
  for (int mt = 0; mt < 4; ++mt) {
    const float* row = Whh + (size_t)(w * 64 + mt * 16 + lr) * HDIM + lq * 128;
    float m = 0.f;
    #pragma unroll 8
    for (int j = 0; j < 128; j += 4) {
      float4v v = *(const float4v*)(row + j);
      m = fmaxf(m, fmaxf(fmaxf(fabsf(v[0]), fabsf(v[1])), fmaxf(fabsf(v[2]), fabsf(v[3]))));
    }
    m = fmaxf(m, __shfl_xor(m, 16));
    m = fmaxf(m, __shfl_xor(m, 32));
    rmax[mt] = fmaxf(m, 1e-20f);
    if (lq == 0) smax[w][mt][lr] = rmax[mt];
  }

  // ---- quantize W fragments: A[row=hcol][k], lane holds k = kc*64+lq*16+0..15 ----
  int4v wq[8][4];
  #pragma unroll
  for (int mt = 0; mt < 4; ++mt) {
    float qs = 127.0f / rmax[mt];
    #pragma unroll
    for (int kc = 0; kc < 8; ++kc) {
      const float* src = Whh + (size_t)(w * 64 + mt * 16 + lr) * HDIM + kc * 64 + lq * 16;
      int4v d;
      #pragma unroll
      for (int dw = 0; dw < 4; ++dw) {
        float4v v = *(const float4v*)(src + dw * 4);
        int b0 = (int)__builtin_rintf(v[0] * qs);
        int b1 = (int)__builtin_rintf(v[1] * qs);
        int b2 = (int)__builtin_rintf(v[2] * qs);
        int b3 = (int)__builtin_rintf(v[3] * qs);
        d[dw] = (b0 & 255) | ((b1 & 255) << 8) | ((b2 & 255) << 16) | (b3 << 24);
      }
      wq[kc][mt] = d;
    }
  }

  for (int i = tid; i < 2 * 16 * 544 / 4; i += 512) ((int*)h8)[i] = 0;
  __syncthreads();

  // dequant scales for this lane's D rows: hcol = w*64+mt*16+lq*4+r
  float4v sc[4];
  #pragma unroll
  for (int mt = 0; mt < 4; ++mt)
    #pragma unroll
    for (int r = 0; r < 4; ++r)
      sc[mt][r] = smax[w][mt][lq * 4 + r] * (1.0f / 16129.0f);   // rowmax/(127*127)

  const unsigned int* xpb = xp + (size_t)(g * 4096 + w * 512 + l);
  const float C2 = 2.8853900818f;   // 2/ln2

  const int rbase = lr * 544 + lq * 16;          // b-frag read base (byte)
  const int wbase = lr * 544 + w * 64 + lq * 4;  // h write base (byte)

  // one half-step: read h8[br], write h8[br^1], consume uc, prefetch t=tpref
  auto half = [&](int br, uintx8 uc, int tpref) -> uintx8 {
    const unsigned int* p = xpb + (size_t)tpref * 16384;
    uintx8 un;
    #pragma unroll
    for (int j = 0; j < 8; ++j) un[j] = p[j * 64];

    int4v acc[4];
    #pragma unroll
    for (int kc = 0; kc < 8; ++kc) {
      int4v b = *(const int4v*)&h8[br][rbase + kc * 64];
      #pragma unroll
      for (int mt = 0; mt < 4; ++mt) {
        int4v c = (kc == 0) ? (int4v){0, 0, 0, 0} : acc[mt];
        acc[mt] = __builtin_amdgcn_mfma_i32_16x16x64_i8(wq[kc][mt], b, c, 0, 0, 0);
      }
    }

    #pragma unroll
    for (int mt = 0; mt < 4; ++mt) {
      unsigned int ua = uc[2 * mt], ub = uc[2 * mt + 1];
      float p0 = (float)acc[mt][0] * sc[mt][0] + __uint_as_float(ua << 16);
      float p1 = (float)acc[mt][1] * sc[mt][1] + __uint_as_float(ua & 0xffff0000u);
      float p2 = (float)acc[mt][2] * sc[mt][2] + __uint_as_float(ub << 16);
      float p3 = (float)acc[mt][3] * sc[mt][3] + __uint_as_float(ub & 0xffff0000u);
      float r0 = __builtin_amdgcn_rcpf(exp2f(p0 * C2) + 1.0f);
      float r1 = __builtin_amdgcn_rcpf(exp2f(p1 * C2) + 1.0f);
      float r2 = __builtin_amdgcn_rcpf(exp2f(p2 * C2) + 1.0f);
      float r3 = __builtin_amdgcn_rcpf(exp2f(p3 * C2) + 1.0f);
      int i0 = (int)__builtin_rintf(127.0f - 254.0f * r0);
      int i1 = (int)__builtin_rintf(127.0f - 254.0f * r1);
      int i2 = (int)__builtin_rintf(127.0f - 254.0f * r2);
      int i3 = (int)__builtin_rintf(127.0f - 254.0f * r3);
      unsigned int pk = (i0 & 255) | ((i1 & 255) << 8) | ((i2 & 255) << 16) | (i3 << 24);
      *(unsigned int*)&h8[br ^ 1][wbase + mt * 16] = pk;
    }
    __syncthreads();
    return un;
  };

  uintx8 ucur;
  #pragma unroll
  for (int j = 0; j < 8; ++j) ucur[j] = xpb[j * 64];

  #pragma unroll 1
  for (int t = 0; t < TDIM; t += 2) {
    uintx8 un = half(0, ucur, t + 1);
    int tt = (t + 2 < TDIM) ? (t + 2) : (TDIM - 1);
    ucur = half(1, un, tt);
  }
  // final h is in h8[0]

  // ---- hT (output 1) + bf16 h for the projection ----
  for (int i = tid; i < 16 * 512; i += 512) {
    int row = i >> 9, col = i & 511;
    float f = (float)((signed char)h8[0][row * 544 + col]) * (1.0f / 127.0f);
    out[(size_t)ODIM * BDIM + ((size_t)(g * 16 + row)) * HDIM + col] = f;
    hbf[row * 520 + col] = (short)f2bf(f);
  }
  __syncthreads();

  // ---- output projection: D[batch][o] = h[batch][:] . Who[o][:] ----
  floatx4 oacc;
  #pragma unroll
  for (int kc = 0; kc < 16; ++kc) {
    short8 a = *(const short8*)&hbf[lr * 520 + kc * 32 + lq * 8];
    int o = w * 16 + lr;
    const float* src = Who + (size_t)o * HDIM + kc * 32 + lq * 8;
    float4v f0 = *(const float4v*)src;
    float4v f1 = *(const float4v*)(src + 4);
    short8 s;
    s[0] = (short)f2bf(f0[0]); s[1] = (short)f2bf(f0[1]);
    s[2] = (short)f2bf(f0[2]); s[3] = (short)f2bf(f0[3]);
    s[4] = (short)f2bf(f1[0]); s[5] = (short)f2bf(f1[1]);
    s[6] = (short)f2bf(f1[2]); s[7] = (short)f2bf(f1[3]);
    floatx4 c = (kc == 0) ? (floatx4){0.f, 0.f, 0.f, 0.f} : oacc;
    oacc = __builtin_amdgcn_mfma_f32_16x16x32_bf16(a, s, c, 0, 0, 0);
  }
  #pragma unroll
  for (int rr = 0; rr < 4; ++rr) {
    int o = w * 16 + lr;
    int row = lq * 4 + rr;
    out[((size_t)(g * 16 + row)) * ODIM + o] = oacc[rr] + bho[o];
  }
}

// ---------------------------------------------------------------------------
extern "C" void kernel_launch(void* const* d_in, const int* in_sizes, int n_in,
                              void* d_out, int out_size, void* d_ws, size_t ws_size,
                              hipStream_t stream) {
  const float* x   = (const float*)d_in[0];
  const float* bd  = (const float*)d_in[1];
  const float* Wih = (const float*)d_in[2];
  const float* bih = (const float*)d_in[3];
  const float* Whh = (const float*)d_in[4];
  const float* bhh = (const float*)d_in[5];
  const float* Who = (const float*)d_in[6];
  const float* bho = (const float*)d_in[7];
  float* out = (float*)d_out;
  unsigned int* xp = (unsigned int*)d_ws;   // T*B*H*2 = 268.4 MB

  prep_kernel<<<dim3(TDIM / 16, 4), 512, 0, stream>>>(x, bd, Wih, bih, bhh, xp);
  scan_kernel<<<dim3(4), 512, 0, stream>>>(Whh, xp, Who, bho, out);
}